// Round 2
// baseline (842.871 us; speedup 1.0000x reference)
//
#include <hip/hip_runtime.h>

// MixtralSparseMoeBlock on gfx950.
// Inputs (fp32): hidden_states [2,2048,1024], gate_w [1024,8],
//                w1 [8,1024,3584], w3 [8,1024,3584], w2 [8,3584,1024]
// Output (fp32): final_hidden [2,2048,1024] ++ router_logits [2,2048,8]
//
// Sparse top-2: router -> per-expert gather -> bf16 MFMA GEMMs (128x128xBK32,
// global_load_lds, XOR bank swizzle, double-buffered 2-phase staging)
// -> gemm2 epilogue does the weighted combine via atomicAdd (2 adds/element,
// fp32 add commutative -> deterministic).

typedef __bf16 v8bf __attribute__((ext_vector_type(8)));
typedef float  v4f  __attribute__((ext_vector_type(4)));

constexpr int kT = 4096;   // tokens = B*S
constexpr int kH = 1024;
constexpr int kI = 3584;
constexpr int kE = 8;

// ---- workspace layout (bytes) ----
constexpr size_t SZ_W    = (size_t)kE * kI * kH * 2;          // one bf16 weight set
constexpr size_t OFF_W1T = 0;                                  // [E][I][H] bf16
constexpr size_t OFF_W3T = OFF_W1T + SZ_W;                     // [E][I][H] bf16
constexpr size_t OFF_W2T = OFF_W3T + SZ_W;                     // [E][H][I] bf16
constexpr size_t OFF_XG  = OFF_W2T + SZ_W;                     // [2T][H] bf16 gathered tokens
constexpr size_t OFF_ACT = OFF_XG  + (size_t)2*kT*kH*2;        // [2T][I] bf16 silu(h1)*h3
constexpr size_t OFF_BUF = OFF_ACT + (size_t)2*kT*kI*2;        // (spare; no longer used)
constexpr size_t OFF_CNT = OFF_BUF + (size_t)2*kT*kH*4;        // int[8] counts
constexpr size_t OFF_OFS = OFF_CNT + 128;                      // int[8] offsets
constexpr size_t OFF_LST = OFF_OFS + 128;                      // int[E][T] token list (t*2+k)
constexpr size_t OFF_TW  = OFF_LST + (size_t)kE*kT*4;          // float[T][2] routing weights
constexpr size_t OFF_GE  = OFF_TW  + (size_t)kT*2*4;           // int[2T] global row -> entry

__device__ __forceinline__ void async16(void* lds, const void* g) {
    __builtin_amdgcn_global_load_lds(
        (const __attribute__((address_space(1))) unsigned int*)g,
        (__attribute__((address_space(3))) unsigned int*)lds,
        16, 0, 0);
}

// ---------------------------------------------------------------- utility
__global__ void zero_counts_kernel(int* __restrict__ counts) {
    if (threadIdx.x < kE) counts[threadIdx.x] = 0;
}

__global__ void prefix_kernel(const int* __restrict__ counts, int* __restrict__ offsets) {
    if (threadIdx.x == 0) {
        int o = 0;
        for (int e = 0; e < kE; e++) { offsets[e] = o; o += counts[e]; }
    }
}

// ---------------------------------------------------------------- router
// one wave per token; fp64 accumulation so top-2 selection is stable vs np ref
__global__ void router_kernel(const float* __restrict__ x, const float* __restrict__ gw,
                              float* __restrict__ logits_out, float* __restrict__ tw,
                              int* __restrict__ counts, int* __restrict__ list) {
    const int wave = threadIdx.x >> 6;
    const int lane = threadIdx.x & 63;
    const int t = blockIdx.x * 4 + wave;
    const float* xr = x + (size_t)t * kH;

    double acc[kE];
#pragma unroll
    for (int e = 0; e < kE; e++) acc[e] = 0.0;

    for (int j = 0; j < kH / 64; j++) {
        const int h = j * 64 + lane;
        const float xv = xr[h];
        const float* g = gw + (size_t)h * kE;
#pragma unroll
        for (int e = 0; e < kE; e++) acc[e] += (double)xv * (double)g[e];
    }
#pragma unroll
    for (int e = 0; e < kE; e++) {
#pragma unroll
        for (int o = 32; o > 0; o >>= 1) acc[e] += __shfl_xor(acc[e], o, 64);
    }

    if (lane == 0) {
        float lg[kE];
#pragma unroll
        for (int e = 0; e < kE; e++) lg[e] = (float)acc[e];
#pragma unroll
        for (int e = 0; e < kE; e++) logits_out[(size_t)t * kE + e] = lg[e];

        // top-2, first-index-wins on ties (np/jax semantics)
        int e0 = 0; float l0 = lg[0];
        for (int e = 1; e < kE; e++) if (lg[e] > l0) { l0 = lg[e]; e0 = e; }
        int e1 = -1; float l1 = -3.4e38f;
        for (int e = 0; e < kE; e++) if (e != e0 && lg[e] > l1) { l1 = lg[e]; e1 = e; }

        const float ex = __expf(l1 - l0);       // l1 <= l0
        const float w0 = 1.0f / (1.0f + ex);
        const float w1 = ex / (1.0f + ex);

        int s0 = atomicAdd(&counts[e0], 1);
        list[e0 * kT + s0] = t * 2 + 0;
        tw[t * 2 + 0] = w0;
        int s1 = atomicAdd(&counts[e1], 1);
        list[e1 * kT + s1] = t * 2 + 1;
        tw[t * 2 + 1] = w1;
    }
}

// ---------------------------------------------------------------- gather
// one block per global row (exactly 2T rows total)
__global__ void gather_kernel(const float* __restrict__ x, const int* __restrict__ list,
                              const int* __restrict__ counts, const int* __restrict__ offsets,
                              __bf16* __restrict__ xg, int* __restrict__ gentry) {
    const int g = blockIdx.x;                 // 0..2T-1
    int e = 0;
    while (e < kE - 1 && g >= offsets[e] + counts[e]) e++;
    const int s = g - offsets[e];
    const int entry = list[e * kT + s];
    const int t = entry >> 1;
    if (threadIdx.x == 0) gentry[g] = entry;  // inverse map for gemm2 scatter
    const int i = threadIdx.x * 4;
    const float4 v = *(const float4*)&x[(size_t)t * kH + i];
    __bf16 pk[4] = {(__bf16)v.x, (__bf16)v.y, (__bf16)v.z, (__bf16)v.w};
    *(ushort4*)&xg[(size_t)g * kH + i] = *(const ushort4*)pk;
}

// ---------------------------------------------------------------- weight transpose + cvt
// fp32 [R][C] -> bf16 [C][R], 64x64 tiles, float4 reads, ushort4 writes.
// z < nz selects (srcA,dstA) expert z, else (srcB,dstB) expert z-nz.
__global__ void transpose_cvt_kernel(const float* __restrict__ srcA, const float* __restrict__ srcB,
                                     __bf16* __restrict__ dstA, __bf16* __restrict__ dstB,
                                     int R, int C, int nz) {
    __shared__ float tile[64][65];
    const int z = blockIdx.z;
    const float* s;
    __bf16* d;
    if (z < nz) { s = srcA + (size_t)z * R * C;        d = dstA + (size_t)z * R * C; }
    else        { s = srcB + (size_t)(z - nz) * R * C; d = dstB + (size_t)(z - nz) * R * C; }
    const int r0 = blockIdx.y * 64, c0 = blockIdx.x * 64;
    const int tr = threadIdx.x >> 4;          // 0..15
    const int tc = (threadIdx.x & 15) * 4;    // 0,4,..,60
#pragma unroll
    for (int i = 0; i < 4; i++) {
        const float4 v = *(const float4*)&s[(size_t)(r0 + tr + i * 16) * C + (c0 + tc)];
        tile[tr + i * 16][tc + 0] = v.x;
        tile[tr + i * 16][tc + 1] = v.y;
        tile[tr + i * 16][tc + 2] = v.z;
        tile[tr + i * 16][tc + 3] = v.w;
    }
    __syncthreads();
#pragma unroll
    for (int i = 0; i < 4; i++) {
        const int oc = tr + i * 16;           // src col within tile = dst row
        __bf16 pk[4] = {(__bf16)tile[tc + 0][oc], (__bf16)tile[tc + 1][oc],
                        (__bf16)tile[tc + 2][oc], (__bf16)tile[tc + 3][oc]};
        *(ushort4*)&d[(size_t)(c0 + oc) * R + r0 + tc] = *(const ushort4*)pk;
    }
}

// ---------------------------------------------------------------- GEMM1 (dual-B, fused silu*mul)
// C1 = Xg @ W1t, C3 = Xg @ W3t ; act = bf16(silu(C1)*C3)
// LDS XOR swizzle: slot (row,c) holds global phase c ^ (row&3) ^ ((row>>2)&3);
// both sides reduce to per-lane constants (see staging scol / fragment sw).
// 2-phase double-buffered staging: issue global_load_lds for K-step kt+1 into
// buf^1 BEFORE computing kt, so the vmcnt(0) drain at the end-of-iteration
// barrier lands after ~300cy of ds_read+MFMA. One barrier per K-step.
__global__ __launch_bounds__(256, 2) void gemm1_kernel(
    const __bf16* __restrict__ xg, const __bf16* __restrict__ w1t,
    const __bf16* __restrict__ w3t, __bf16* __restrict__ act,
    const int* __restrict__ counts, const int* __restrict__ offsets) {
    const int e = blockIdx.z;
    const int cnt = counts[e];
    const int m0 = blockIdx.y * 128;
    if (m0 >= cnt) return;
    const int n0 = blockIdx.x * 128;
    const int off = offsets[e];

    // double-buffered: [2][128*32] each
    __shared__ __bf16 As[2 * 4096], B1s[2 * 4096], B3s[2 * 4096];

    const int tid = threadIdx.x;
    const int lane = tid & 63, wave = tid >> 6;
    const int wm = (wave >> 1) * 64, wn = (wave & 1) * 64;
    const int lrow = lane & 15, quad = lane >> 4;

    // staging: lane stages LDS slot (row = p*64 + tid/4, phase = tid&3) and must
    // fetch global phase (tid&3) ^ ((tid>>2)&3) ^ ((tid>>4)&3)
    const int scol = (((tid & 3) ^ ((tid >> 2) & 3) ^ ((tid >> 4) & 3))) * 8;
    const __bf16* abase[2];
    const __bf16* b1base[2];
    const __bf16* b3base[2];
    const __bf16* w1b = w1t + (size_t)e * kI * kH + (size_t)n0 * kH;
    const __bf16* w3b = w3t + (size_t)e * kI * kH + (size_t)n0 * kH;
#pragma unroll
    for (int p = 0; p < 2; p++) {
        const int r = p * 64 + (tid >> 2);
        const int gr = min(m0 + r, cnt - 1);           // clamp for partial tiles
        abase[p]  = xg + (size_t)(off + gr) * kH + scol;
        b1base[p] = w1b + (size_t)r * kH + scol;
        b3base[p] = w3b + (size_t)r * kH + scol;
    }

    // fragment reads: swizzled phase = quad ^ (lrow&3) ^ ((lrow>>2)&3)
    const int sw = (lane & 3) ^ ((lane >> 2) & 3);
    const int fragoff = lrow * 32 + ((quad ^ sw) * 8);

    v4f acc1[4][4], acc3[4][4];
#pragma unroll
    for (int i = 0; i < 4; i++)
#pragma unroll
        for (int j = 0; j < 4; j++) { acc1[i][j] = (v4f)0.0f; acc3[i][j] = (v4f)0.0f; }

    constexpr int NK = kH / 32;

    // prologue: stage kt=0 into buf 0
#pragma unroll
    for (int p = 0; p < 2; p++) {
        const int soff = p * 2048 + tid * 8;
        async16(&As[soff],  abase[p]);
        async16(&B1s[soff], b1base[p]);
        async16(&B3s[soff], b3base[p]);
    }
    __syncthreads();

    int cur = 0;
    for (int kt = 0; kt < NK; kt++) {
        // prefetch next K-step into the other buffer (in flight during compute)
        if (kt + 1 < NK) {
            const int k0n = (kt + 1) * 32;
            const int nb = (cur ^ 1) * 4096;
#pragma unroll
            for (int p = 0; p < 2; p++) {
                const int soff = nb + p * 2048 + tid * 8;
                async16(&As[soff],  abase[p]  + k0n);
                async16(&B1s[soff], b1base[p] + k0n);
                async16(&B3s[soff], b3base[p] + k0n);
            }
        }

        const int base = cur * 4096;
        v8bf a[4];
#pragma unroll
        for (int fm = 0; fm < 4; fm++)
            a[fm] = *(const v8bf*)&As[base + (wm + fm * 16) * 32 + fragoff];
#pragma unroll
        for (int fn = 0; fn < 4; fn++) {
            const v8bf b1 = *(const v8bf*)&B1s[base + (wn + fn * 16) * 32 + fragoff];
            const v8bf b3 = *(const v8bf*)&B3s[base + (wn + fn * 16) * 32 + fragoff];
#pragma unroll
            for (int fm = 0; fm < 4; fm++) {
                acc1[fm][fn] = __builtin_amdgcn_mfma_f32_16x16x32_bf16(a[fm], b1, acc1[fm][fn], 0, 0, 0);
                acc3[fm][fn] = __builtin_amdgcn_mfma_f32_16x16x32_bf16(a[fm], b3, acc3[fm][fn], 0, 0, 0);
            }
        }
        // single barrier per K-step: drains next-tile vmcnt (mostly landed) and
        // guards cur^1 overwrite (all waves read it last iteration)
        __syncthreads();
        cur ^= 1;
    }

    // epilogue: silu(c1)*c3 -> bf16 act
#pragma unroll
    for (int fm = 0; fm < 4; fm++) {
#pragma unroll
        for (int fn = 0; fn < 4; fn++) {
            const v4f c1 = acc1[fm][fn], c3 = acc3[fm][fn];
            const int col = n0 + wn + fn * 16 + lrow;
#pragma unroll
            for (int r = 0; r < 4; r++) {
                const int gm = m0 + wm + fm * 16 + quad * 4 + r;
                if (gm < cnt) {
                    const float h1 = c1[r], h3 = c3[r];
                    const float v = h1 / (1.0f + __expf(-h1)) * h3;
                    act[(size_t)(off + gm) * kI + col] = (__bf16)v;
                }
            }
        }
    }
}

// ---------------------------------------------------------------- GEMM2 (+fused combine)
// out[t] += tw[entry] * (act @ W2t)[g]  via atomicAdd; exactly 2 adds/element,
// fp32 add commutative -> bit-deterministic. Same GEMM structure as gemm1.
__global__ __launch_bounds__(256, 3) void gemm2_kernel(
    const __bf16* __restrict__ act, const __bf16* __restrict__ w2t,
    float* __restrict__ out, const float* __restrict__ tw,
    const int* __restrict__ gentry,
    const int* __restrict__ counts, const int* __restrict__ offsets) {
    const int e = blockIdx.z;
    const int cnt = counts[e];
    const int m0 = blockIdx.y * 128;
    if (m0 >= cnt) return;
    const int n0 = blockIdx.x * 128;
    const int off = offsets[e];

    __shared__ __bf16 As[2 * 4096], Bs[2 * 4096];

    const int tid = threadIdx.x;
    const int lane = tid & 63, wave = tid >> 6;
    const int wm = (wave >> 1) * 64, wn = (wave & 1) * 64;
    const int lrow = lane & 15, quad = lane >> 4;

    const int scol = (((tid & 3) ^ ((tid >> 2) & 3) ^ ((tid >> 4) & 3))) * 8;
    const __bf16* abase[2];
    const __bf16* bbase[2];
    const __bf16* w2b = w2t + (size_t)e * kH * kI + (size_t)n0 * kI;
#pragma unroll
    for (int p = 0; p < 2; p++) {
        const int r = p * 64 + (tid >> 2);
        const int gr = min(m0 + r, cnt - 1);
        abase[p] = act + (size_t)(off + gr) * kI + scol;
        bbase[p] = w2b + (size_t)r * kI + scol;
    }

    const int sw = (lane & 3) ^ ((lane >> 2) & 3);
    const int fragoff = lrow * 32 + ((quad ^ sw) * 8);

    v4f acc[4][4];
#pragma unroll
    for (int i = 0; i < 4; i++)
#pragma unroll
        for (int j = 0; j < 4; j++) acc[i][j] = (v4f)0.0f;

    constexpr int NK = kI / 32;

    // prologue
#pragma unroll
    for (int p = 0; p < 2; p++) {
        const int soff = p * 2048 + tid * 8;
        async16(&As[soff], abase[p]);
        async16(&Bs[soff], bbase[p]);
    }
    __syncthreads();

    int cur = 0;
    for (int kt = 0; kt < NK; kt++) {
        if (kt + 1 < NK) {
            const int k0n = (kt + 1) * 32;
            const int nb = (cur ^ 1) * 4096;
#pragma unroll
            for (int p = 0; p < 2; p++) {
                const int soff = nb + p * 2048 + tid * 8;
                async16(&As[soff], abase[p] + k0n);
                async16(&Bs[soff], bbase[p] + k0n);
            }
        }

        const int base = cur * 4096;
        v8bf a[4];
#pragma unroll
        for (int fm = 0; fm < 4; fm++)
            a[fm] = *(const v8bf*)&As[base + (wm + fm * 16) * 32 + fragoff];
#pragma unroll
        for (int fn = 0; fn < 4; fn++) {
            const v8bf b = *(const v8bf*)&Bs[base + (wn + fn * 16) * 32 + fragoff];
#pragma unroll
            for (int fm = 0; fm < 4; fm++)
                acc[fm][fn] = __builtin_amdgcn_mfma_f32_16x16x32_bf16(a[fm], b, acc[fm][fn], 0, 0, 0);
        }
        __syncthreads();
        cur ^= 1;
    }

    // per-row token + routing weight (16 rows per thread)
    int   tok[4][4];
    float wgt[4][4];
#pragma unroll
    for (int fm = 0; fm < 4; fm++) {
#pragma unroll
        for (int r = 0; r < 4; r++) {
            const int gm = m0 + wm + fm * 16 + quad * 4 + r;
            if (gm < cnt) {
                const int entry = gentry[off + gm];
                tok[fm][r] = entry >> 1;
                wgt[fm][r] = tw[entry];
            } else {
                tok[fm][r] = -1;
                wgt[fm][r] = 0.0f;
            }
        }
    }

#pragma unroll
    for (int fm = 0; fm < 4; fm++) {
#pragma unroll
        for (int fn = 0; fn < 4; fn++) {
            const v4f c = acc[fm][fn];
            const int col = n0 + wn + fn * 16 + lrow;
#pragma unroll
            for (int r = 0; r < 4; r++) {
                if (tok[fm][r] >= 0)
                    atomicAdd(&out[(size_t)tok[fm][r] * kH + col], wgt[fm][r] * c[r]);
            }
        }
    }
}

// ---------------------------------------------------------------- launch
extern "C" void kernel_launch(void* const* d_in, const int* in_sizes, int n_in,
                              void* d_out, int out_size, void* d_ws, size_t ws_size,
                              hipStream_t stream) {
    const float* x  = (const float*)d_in[0];
    const float* gw = (const float*)d_in[1];
    const float* w1 = (const float*)d_in[2];
    const float* w3 = (const float*)d_in[3];
    const float* w2 = (const float*)d_in[4];
    float* out = (float*)d_out;
    float* logits_out = out + (size_t)kT * kH;

    char* ws = (char*)d_ws;
    __bf16* w1t   = (__bf16*)(ws + OFF_W1T);
    __bf16* w3t   = (__bf16*)(ws + OFF_W3T);
    __bf16* w2t   = (__bf16*)(ws + OFF_W2T);
    __bf16* xg    = (__bf16*)(ws + OFF_XG);
    __bf16* act   = (__bf16*)(ws + OFF_ACT);
    int*    cnt   = (int*)   (ws + OFF_CNT);
    int*    ofs   = (int*)   (ws + OFF_OFS);
    int*    list  = (int*)   (ws + OFF_LST);
    float*  tw    = (float*) (ws + OFF_TW);
    int*    gent  = (int*)   (ws + OFF_GE);

    zero_counts_kernel<<<1, 64, 0, stream>>>(cnt);
    // zero the hidden-state part of out (gemm2 accumulates into it atomically)
    hipMemsetAsync(out, 0, (size_t)kT * kH * sizeof(float), stream);

    // w1 [H][I] -> [I][H] and w3 likewise, fused in one launch (z = 16)
    transpose_cvt_kernel<<<dim3(kI / 64, kH / 64, 2 * kE), 256, 0, stream>>>(
        w1, w3, w1t, w3t, kH, kI, kE);
    // w2 [I][H] -> [H][I]
    transpose_cvt_kernel<<<dim3(kH / 64, kI / 64, kE), 256, 0, stream>>>(
        w2, w2, w2t, w2t, kI, kH, kE);

    router_kernel<<<kT / 4, 256, 0, stream>>>(x, gw, logits_out, tw, cnt, list);
    prefix_kernel<<<1, 1, 0, stream>>>(cnt, ofs);
    gather_kernel<<<2 * kT, 256, 0, stream>>>(x, list, cnt, ofs, xg, gent);

    gemm1_kernel<<<dim3(kI / 128, kT / 128, kE), 256, 0, stream>>>(xg, w1t, w3t, act, cnt, ofs);
    gemm2_kernel<<<dim3(kH / 128, kT / 128, kE), 256, 0, stream>>>(act, w2t, out, tw, gent, cnt, ofs);
}

// Round 3
// 796.972 us; speedup vs baseline: 1.0576x; 1.0576x over previous
//
#include <hip/hip_runtime.h>

// MixtralSparseMoeBlock on gfx950.
// Inputs (fp32): hidden_states [2,2048,1024], gate_w [1024,8],
//                w1 [8,1024,3584], w3 [8,1024,3584], w2 [8,3584,1024]
// Output (fp32): final_hidden [2,2048,1024] ++ router_logits [2,2048,8]
//
// Sparse top-2: router -> per-expert gather -> bf16 MFMA GEMMs (128x128xBK32,
// global_load_lds, XOR bank swizzle, single-buffered: 24/16 KB LDS keeps
// ~5 blocks/CU resident for latency hiding — dbuf at 48 KB dropped to 3
// blocks/CU and regressed, round-2 counters) -> gemm2 epilogue does the
// weighted combine via atomicAdd (2 adds/element, fp32 add commutative ->
// deterministic).

typedef __bf16 v8bf __attribute__((ext_vector_type(8)));
typedef float  v4f  __attribute__((ext_vector_type(4)));

constexpr int kT = 4096;   // tokens = B*S
constexpr int kH = 1024;
constexpr int kI = 3584;
constexpr int kE = 8;

// ---- workspace layout (bytes) ----
constexpr size_t SZ_W    = (size_t)kE * kI * kH * 2;          // one bf16 weight set
constexpr size_t OFF_W1T = 0;                                  // [E][I][H] bf16
constexpr size_t OFF_W3T = OFF_W1T + SZ_W;                     // [E][I][H] bf16
constexpr size_t OFF_W2T = OFF_W3T + SZ_W;                     // [E][H][I] bf16
constexpr size_t OFF_XG  = OFF_W2T + SZ_W;                     // [2T][H] bf16 gathered tokens
constexpr size_t OFF_ACT = OFF_XG  + (size_t)2*kT*kH*2;        // [2T][I] bf16 silu(h1)*h3
constexpr size_t OFF_BUF = OFF_ACT + (size_t)2*kT*kI*2;        // (spare)
constexpr size_t OFF_CNT = OFF_BUF + (size_t)2*kT*kH*4;        // int[8] counts
constexpr size_t OFF_OFS = OFF_CNT + 128;                      // int[8] offsets
constexpr size_t OFF_LST = OFF_OFS + 128;                      // int[E][T] token list (t*2+k)
constexpr size_t OFF_TW  = OFF_LST + (size_t)kE*kT*4;          // float[T][2] routing weights
constexpr size_t OFF_GE  = OFF_TW  + (size_t)kT*2*4;           // int[2T] global row -> entry

__device__ __forceinline__ void async16(void* lds, const void* g) {
    __builtin_amdgcn_global_load_lds(
        (const __attribute__((address_space(1))) unsigned int*)g,
        (__attribute__((address_space(3))) unsigned int*)lds,
        16, 0, 0);
}

// ---------------------------------------------------------------- utility
__global__ void zero_counts_kernel(int* __restrict__ counts) {
    if (threadIdx.x < kE) counts[threadIdx.x] = 0;
}

__global__ void prefix_kernel(const int* __restrict__ counts, int* __restrict__ offsets) {
    if (threadIdx.x == 0) {
        int o = 0;
        for (int e = 0; e < kE; e++) { offsets[e] = o; o += counts[e]; }
    }
}

// ---------------------------------------------------------------- router
// one wave per token; fp64 accumulation so top-2 selection is stable vs np ref
__global__ void router_kernel(const float* __restrict__ x, const float* __restrict__ gw,
                              float* __restrict__ logits_out, float* __restrict__ tw,
                              int* __restrict__ counts, int* __restrict__ list) {
    const int wave = threadIdx.x >> 6;
    const int lane = threadIdx.x & 63;
    const int t = blockIdx.x * 4 + wave;
    const float* xr = x + (size_t)t * kH;

    double acc[kE];
#pragma unroll
    for (int e = 0; e < kE; e++) acc[e] = 0.0;

    for (int j = 0; j < kH / 64; j++) {
        const int h = j * 64 + lane;
        const float xv = xr[h];
        const float* g = gw + (size_t)h * kE;
#pragma unroll
        for (int e = 0; e < kE; e++) acc[e] += (double)xv * (double)g[e];
    }
#pragma unroll
    for (int e = 0; e < kE; e++) {
#pragma unroll
        for (int o = 32; o > 0; o >>= 1) acc[e] += __shfl_xor(acc[e], o, 64);
    }

    if (lane == 0) {
        float lg[kE];
#pragma unroll
        for (int e = 0; e < kE; e++) lg[e] = (float)acc[e];
#pragma unroll
        for (int e = 0; e < kE; e++) logits_out[(size_t)t * kE + e] = lg[e];

        // top-2, first-index-wins on ties (np/jax semantics)
        int e0 = 0; float l0 = lg[0];
        for (int e = 1; e < kE; e++) if (lg[e] > l0) { l0 = lg[e]; e0 = e; }
        int e1 = -1; float l1 = -3.4e38f;
        for (int e = 0; e < kE; e++) if (e != e0 && lg[e] > l1) { l1 = lg[e]; e1 = e; }

        const float ex = __expf(l1 - l0);       // l1 <= l0
        const float w0 = 1.0f / (1.0f + ex);
        const float w1 = ex / (1.0f + ex);

        int s0 = atomicAdd(&counts[e0], 1);
        list[e0 * kT + s0] = t * 2 + 0;
        tw[t * 2 + 0] = w0;
        int s1 = atomicAdd(&counts[e1], 1);
        list[e1 * kT + s1] = t * 2 + 1;
        tw[t * 2 + 1] = w1;
    }
}

// ---------------------------------------------------------------- gather
// one block per global row (exactly 2T rows total)
__global__ void gather_kernel(const float* __restrict__ x, const int* __restrict__ list,
                              const int* __restrict__ counts, const int* __restrict__ offsets,
                              __bf16* __restrict__ xg, int* __restrict__ gentry) {
    const int g = blockIdx.x;                 // 0..2T-1
    int e = 0;
    while (e < kE - 1 && g >= offsets[e] + counts[e]) e++;
    const int s = g - offsets[e];
    const int entry = list[e * kT + s];
    const int t = entry >> 1;
    if (threadIdx.x == 0) gentry[g] = entry;  // inverse map for gemm2 scatter
    const int i = threadIdx.x * 4;
    const float4 v = *(const float4*)&x[(size_t)t * kH + i];
    __bf16 pk[4] = {(__bf16)v.x, (__bf16)v.y, (__bf16)v.z, (__bf16)v.w};
    *(ushort4*)&xg[(size_t)g * kH + i] = *(const ushort4*)pk;
}

// ---------------------------------------------------------------- weight transpose + cvt
// fp32 [R][C] -> bf16 [C][R], 64x64 tiles, float4 reads, ushort4 writes.
// z < nz selects (srcA,dstA) expert z, else (srcB,dstB) expert z-nz.
__global__ void transpose_cvt_kernel(const float* __restrict__ srcA, const float* __restrict__ srcB,
                                     __bf16* __restrict__ dstA, __bf16* __restrict__ dstB,
                                     int R, int C, int nz) {
    __shared__ float tile[64][65];
    const int z = blockIdx.z;
    const float* s;
    __bf16* d;
    if (z < nz) { s = srcA + (size_t)z * R * C;        d = dstA + (size_t)z * R * C; }
    else        { s = srcB + (size_t)(z - nz) * R * C; d = dstB + (size_t)(z - nz) * R * C; }
    const int r0 = blockIdx.y * 64, c0 = blockIdx.x * 64;
    const int tr = threadIdx.x >> 4;          // 0..15
    const int tc = (threadIdx.x & 15) * 4;    // 0,4,..,60
#pragma unroll
    for (int i = 0; i < 4; i++) {
        const float4 v = *(const float4*)&s[(size_t)(r0 + tr + i * 16) * C + (c0 + tc)];
        tile[tr + i * 16][tc + 0] = v.x;
        tile[tr + i * 16][tc + 1] = v.y;
        tile[tr + i * 16][tc + 2] = v.z;
        tile[tr + i * 16][tc + 3] = v.w;
    }
    __syncthreads();
#pragma unroll
    for (int i = 0; i < 4; i++) {
        const int oc = tr + i * 16;           // src col within tile = dst row
        __bf16 pk[4] = {(__bf16)tile[tc + 0][oc], (__bf16)tile[tc + 1][oc],
                        (__bf16)tile[tc + 2][oc], (__bf16)tile[tc + 3][oc]};
        *(ushort4*)&d[(size_t)(c0 + oc) * R + r0 + tc] = *(const ushort4*)pk;
    }
}

// ---------------------------------------------------------------- GEMM1 (dual-B, fused silu*mul)
// C1 = Xg @ W1t, C3 = Xg @ W3t ; act = bf16(silu(C1)*C3)
// LDS XOR swizzle: slot (row,c) holds global phase c ^ (row&3) ^ ((row>>2)&3);
// both sides reduce to per-lane constants (see staging scol / fragment sw).
// Single-buffered (24 KB LDS): ~5 blocks/CU resident; wave-level overlap
// across 20 waves/CU does the latency hiding (m114/m97 pattern).
__global__ __launch_bounds__(256, 2) void gemm1_kernel(
    const __bf16* __restrict__ xg, const __bf16* __restrict__ w1t,
    const __bf16* __restrict__ w3t, __bf16* __restrict__ act,
    const int* __restrict__ counts, const int* __restrict__ offsets) {
    const int e = blockIdx.z;
    const int cnt = counts[e];
    const int m0 = blockIdx.y * 128;
    if (m0 >= cnt) return;
    const int n0 = blockIdx.x * 128;
    const int off = offsets[e];

    __shared__ __bf16 As[128 * 32], B1s[128 * 32], B3s[128 * 32];

    const int tid = threadIdx.x;
    const int lane = tid & 63, wave = tid >> 6;
    const int wm = (wave >> 1) * 64, wn = (wave & 1) * 64;
    const int lrow = lane & 15, quad = lane >> 4;

    // staging: lane stages LDS slot (row = p*64 + tid/4, phase = tid&3) and must
    // fetch global phase (tid&3) ^ ((tid>>2)&3) ^ ((tid>>4)&3)
    const int scol = (((tid & 3) ^ ((tid >> 2) & 3) ^ ((tid >> 4) & 3))) * 8;
    const __bf16* abase[2];
    const __bf16* b1base[2];
    const __bf16* b3base[2];
    const __bf16* w1b = w1t + (size_t)e * kI * kH + (size_t)n0 * kH;
    const __bf16* w3b = w3t + (size_t)e * kI * kH + (size_t)n0 * kH;
#pragma unroll
    for (int p = 0; p < 2; p++) {
        const int r = p * 64 + (tid >> 2);
        const int gr = min(m0 + r, cnt - 1);           // clamp for partial tiles
        abase[p]  = xg + (size_t)(off + gr) * kH + scol;
        b1base[p] = w1b + (size_t)r * kH + scol;
        b3base[p] = w3b + (size_t)r * kH + scol;
    }

    // fragment reads: swizzled phase = quad ^ (lrow&3) ^ ((lrow>>2)&3)
    const int sw = (lane & 3) ^ ((lane >> 2) & 3);
    const int fragoff = lrow * 32 + ((quad ^ sw) * 8);

    v4f acc1[4][4], acc3[4][4];
#pragma unroll
    for (int i = 0; i < 4; i++)
#pragma unroll
        for (int j = 0; j < 4; j++) { acc1[i][j] = (v4f)0.0f; acc3[i][j] = (v4f)0.0f; }

    for (int kt = 0; kt < kH / 32; kt++) {
        const int k0 = kt * 32;
#pragma unroll
        for (int p = 0; p < 2; p++) {
            const int soff = p * 2048 + tid * 8;       // elements
            async16(&As[soff],  abase[p]  + k0);
            async16(&B1s[soff], b1base[p] + k0);
            async16(&B3s[soff], b3base[p] + k0);
        }
        __syncthreads();

        v8bf a[4];
#pragma unroll
        for (int fm = 0; fm < 4; fm++)
            a[fm] = *(const v8bf*)&As[(wm + fm * 16) * 32 + fragoff];
#pragma unroll
        for (int fn = 0; fn < 4; fn++) {
            const v8bf b1 = *(const v8bf*)&B1s[(wn + fn * 16) * 32 + fragoff];
            const v8bf b3 = *(const v8bf*)&B3s[(wn + fn * 16) * 32 + fragoff];
#pragma unroll
            for (int fm = 0; fm < 4; fm++) {
                acc1[fm][fn] = __builtin_amdgcn_mfma_f32_16x16x32_bf16(a[fm], b1, acc1[fm][fn], 0, 0, 0);
                acc3[fm][fn] = __builtin_amdgcn_mfma_f32_16x16x32_bf16(a[fm], b3, acc3[fm][fn], 0, 0, 0);
            }
        }
        __syncthreads();
    }

    // epilogue: silu(c1)*c3 -> bf16 act
#pragma unroll
    for (int fm = 0; fm < 4; fm++) {
#pragma unroll
        for (int fn = 0; fn < 4; fn++) {
            const v4f c1 = acc1[fm][fn], c3 = acc3[fm][fn];
            const int col = n0 + wn + fn * 16 + lrow;
#pragma unroll
            for (int r = 0; r < 4; r++) {
                const int gm = m0 + wm + fm * 16 + quad * 4 + r;
                if (gm < cnt) {
                    const float h1 = c1[r], h3 = c3[r];
                    const float v = h1 / (1.0f + __expf(-h1)) * h3;
                    act[(size_t)(off + gm) * kI + col] = (__bf16)v;
                }
            }
        }
    }
}

// ---------------------------------------------------------------- GEMM2 (+fused combine)
// out[t] += tw[entry] * (act @ W2t)[g]  via atomicAdd; exactly 2 adds/element,
// fp32 add commutative -> bit-deterministic. Single-buffered (16 KB LDS).
// Row lookups inlined in the store loop (no tok/wgt register arrays; 16 lanes
// sharing a row broadcast the same gentry/tw load).
__global__ __launch_bounds__(256, 2) void gemm2_kernel(
    const __bf16* __restrict__ act, const __bf16* __restrict__ w2t,
    float* __restrict__ out, const float* __restrict__ tw,
    const int* __restrict__ gentry,
    const int* __restrict__ counts, const int* __restrict__ offsets) {
    const int e = blockIdx.z;
    const int cnt = counts[e];
    const int m0 = blockIdx.y * 128;
    if (m0 >= cnt) return;
    const int n0 = blockIdx.x * 128;
    const int off = offsets[e];

    __shared__ __bf16 As[128 * 32], Bs[128 * 32];

    const int tid = threadIdx.x;
    const int lane = tid & 63, wave = tid >> 6;
    const int wm = (wave >> 1) * 64, wn = (wave & 1) * 64;
    const int lrow = lane & 15, quad = lane >> 4;

    const int scol = (((tid & 3) ^ ((tid >> 2) & 3) ^ ((tid >> 4) & 3))) * 8;
    const __bf16* abase[2];
    const __bf16* bbase[2];
    const __bf16* w2b = w2t + (size_t)e * kH * kI + (size_t)n0 * kI;
#pragma unroll
    for (int p = 0; p < 2; p++) {
        const int r = p * 64 + (tid >> 2);
        const int gr = min(m0 + r, cnt - 1);
        abase[p] = act + (size_t)(off + gr) * kI + scol;
        bbase[p] = w2b + (size_t)r * kI + scol;
    }

    const int sw = (lane & 3) ^ ((lane >> 2) & 3);
    const int fragoff = lrow * 32 + ((quad ^ sw) * 8);

    v4f acc[4][4];
#pragma unroll
    for (int i = 0; i < 4; i++)
#pragma unroll
        for (int j = 0; j < 4; j++) acc[i][j] = (v4f)0.0f;

    for (int kt = 0; kt < kI / 32; kt++) {
        const int k0 = kt * 32;
#pragma unroll
        for (int p = 0; p < 2; p++) {
            const int soff = p * 2048 + tid * 8;
            async16(&As[soff], abase[p] + k0);
            async16(&Bs[soff], bbase[p] + k0);
        }
        __syncthreads();

        v8bf a[4];
#pragma unroll
        for (int fm = 0; fm < 4; fm++)
            a[fm] = *(const v8bf*)&As[(wm + fm * 16) * 32 + fragoff];
#pragma unroll
        for (int fn = 0; fn < 4; fn++) {
            const v8bf b = *(const v8bf*)&Bs[(wn + fn * 16) * 32 + fragoff];
#pragma unroll
            for (int fm = 0; fm < 4; fm++)
                acc[fm][fn] = __builtin_amdgcn_mfma_f32_16x16x32_bf16(a[fm], b, acc[fm][fn], 0, 0, 0);
        }
        __syncthreads();
    }

#pragma unroll
    for (int fm = 0; fm < 4; fm++) {
#pragma unroll
        for (int r = 0; r < 4; r++) {
            const int gm = m0 + wm + fm * 16 + quad * 4 + r;
            if (gm < cnt) {
                const int entry = gentry[off + gm];      // broadcast across 16 lanes
                const int t = entry >> 1;
                const float w = tw[entry];
#pragma unroll
                for (int fn = 0; fn < 4; fn++) {
                    const int col = n0 + wn + fn * 16 + lrow;
                    atomicAdd(&out[(size_t)t * kH + col], w * acc[fm][fn][r]);
                }
            }
        }
    }
}

// ---------------------------------------------------------------- launch
extern "C" void kernel_launch(void* const* d_in, const int* in_sizes, int n_in,
                              void* d_out, int out_size, void* d_ws, size_t ws_size,
                              hipStream_t stream) {
    const float* x  = (const float*)d_in[0];
    const float* gw = (const float*)d_in[1];
    const float* w1 = (const float*)d_in[2];
    const float* w3 = (const float*)d_in[3];
    const float* w2 = (const float*)d_in[4];
    float* out = (float*)d_out;
    float* logits_out = out + (size_t)kT * kH;

    char* ws = (char*)d_ws;
    __bf16* w1t   = (__bf16*)(ws + OFF_W1T);
    __bf16* w3t   = (__bf16*)(ws + OFF_W3T);
    __bf16* w2t   = (__bf16*)(ws + OFF_W2T);
    __bf16* xg    = (__bf16*)(ws + OFF_XG);
    __bf16* act   = (__bf16*)(ws + OFF_ACT);
    int*    cnt   = (int*)   (ws + OFF_CNT);
    int*    ofs   = (int*)   (ws + OFF_OFS);
    int*    list  = (int*)   (ws + OFF_LST);
    float*  tw    = (float*) (ws + OFF_TW);
    int*    gent  = (int*)   (ws + OFF_GE);

    zero_counts_kernel<<<1, 64, 0, stream>>>(cnt);
    // zero the hidden-state part of out (gemm2 accumulates into it atomically)
    hipMemsetAsync(out, 0, (size_t)kT * kH * sizeof(float), stream);

    // w1 [H][I] -> [I][H] and w3 likewise, fused in one launch (z = 16)
    transpose_cvt_kernel<<<dim3(kI / 64, kH / 64, 2 * kE), 256, 0, stream>>>(
        w1, w3, w1t, w3t, kH, kI, kE);
    // w2 [I][H] -> [H][I]
    transpose_cvt_kernel<<<dim3(kH / 64, kI / 64, kE), 256, 0, stream>>>(
        w2, w2, w2t, w2t, kI, kH, kE);

    router_kernel<<<kT / 4, 256, 0, stream>>>(x, gw, logits_out, tw, cnt, list);
    prefix_kernel<<<1, 1, 0, stream>>>(cnt, ofs);
    gather_kernel<<<2 * kT, 256, 0, stream>>>(x, list, cnt, ofs, xg, gent);

    gemm1_kernel<<<dim3(kI / 128, kT / 128, kE), 256, 0, stream>>>(xg, w1t, w3t, act, cnt, ofs);
    gemm2_kernel<<<dim3(kH / 128, kT / 128, kE), 256, 0, stream>>>(act, w2t, out, tw, gent, cnt, ofs);
}

// Round 5
// 772.306 us; speedup vs baseline: 1.0914x; 1.0319x over previous
//
#include <hip/hip_runtime.h>

// MixtralSparseMoeBlock on gfx950.
// Inputs (fp32): hidden_states [2,2048,1024], gate_w [1024,8],
//                w1 [8,1024,3584], w3 [8,1024,3584], w2 [8,3584,1024]
// Output (fp32): final_hidden [2,2048,1024] ++ router_logits [2,2048,8]
//
// Sparse top-2: router -> per-expert gather -> bf16 MFMA GEMMs (128x128 tile,
// BK=64 as two 128x32 sub-tiles per barrier pair: halves barrier-drain count;
// global_load_lds + XOR bank swizzle unchanged) -> gemm2 epilogue does the
// weighted combine via atomicAdd (2 adds/element, fp32 add commutative ->
// deterministic).
//
// Occupancy note (round-3 counters): gemm1 is REGISTER-bound at 2 blocks/CU
// (96 VGPR + 128 acc = 224 unified regs), not LDS-bound — 24 vs 48 KB LDS
// made no occupancy difference. So BK=64's extra LDS is free.

typedef __bf16 v8bf __attribute__((ext_vector_type(8)));
typedef float  v4f  __attribute__((ext_vector_type(4)));

constexpr int kT = 4096;   // tokens = B*S
constexpr int kH = 1024;
constexpr int kI = 3584;
constexpr int kE = 8;

// ---- workspace layout (bytes) ----
constexpr size_t SZ_W    = (size_t)kE * kI * kH * 2;          // one bf16 weight set
constexpr size_t OFF_W1T = 0;                                  // [E][I][H] bf16
constexpr size_t OFF_W3T = OFF_W1T + SZ_W;                     // [E][I][H] bf16
constexpr size_t OFF_W2T = OFF_W3T + SZ_W;                     // [E][H][I] bf16
constexpr size_t OFF_XG  = OFF_W2T + SZ_W;                     // [2T][H] bf16 gathered tokens
constexpr size_t OFF_ACT = OFF_XG  + (size_t)2*kT*kH*2;        // [2T][I] bf16 silu(h1)*h3
constexpr size_t OFF_BUF = OFF_ACT + (size_t)2*kT*kI*2;        // (spare)
constexpr size_t OFF_CNT = OFF_BUF + (size_t)2*kT*kH*4;        // int[8] counts
constexpr size_t OFF_OFS = OFF_CNT + 128;                      // int[8] offsets
constexpr size_t OFF_LST = OFF_OFS + 128;                      // int[E][T] token list (t*2+k)
constexpr size_t OFF_TW  = OFF_LST + (size_t)kE*kT*4;          // float[T][2] routing weights
constexpr size_t OFF_GE  = OFF_TW  + (size_t)kT*2*4;           // int[2T] global row -> entry

__device__ __forceinline__ void async16(void* lds, const void* g) {
    __builtin_amdgcn_global_load_lds(
        (const __attribute__((address_space(1))) unsigned int*)g,
        (__attribute__((address_space(3))) unsigned int*)lds,
        16, 0, 0);
}

// ---------------------------------------------------------------- utility
__global__ void zero_counts_kernel(int* __restrict__ counts) {
    if (threadIdx.x < kE) counts[threadIdx.x] = 0;
}

__global__ void prefix_kernel(const int* __restrict__ counts, int* __restrict__ offsets) {
    if (threadIdx.x == 0) {
        int o = 0;
        for (int e = 0; e < kE; e++) { offsets[e] = o; o += counts[e]; }
    }
}

// ---------------------------------------------------------------- router
// one wave per token; fp64 accumulation so top-2 selection is stable vs np ref
__global__ void router_kernel(const float* __restrict__ x, const float* __restrict__ gw,
                              float* __restrict__ logits_out, float* __restrict__ tw,
                              int* __restrict__ counts, int* __restrict__ list) {
    const int wave = threadIdx.x >> 6;
    const int lane = threadIdx.x & 63;
    const int t = blockIdx.x * 4 + wave;
    const float* xr = x + (size_t)t * kH;

    double acc[kE];
#pragma unroll
    for (int e = 0; e < kE; e++) acc[e] = 0.0;

    for (int j = 0; j < kH / 64; j++) {
        const int h = j * 64 + lane;
        const float xv = xr[h];
        const float* g = gw + (size_t)h * kE;
#pragma unroll
        for (int e = 0; e < kE; e++) acc[e] += (double)xv * (double)g[e];
    }
#pragma unroll
    for (int e = 0; e < kE; e++) {
#pragma unroll
        for (int o = 32; o > 0; o >>= 1) acc[e] += __shfl_xor(acc[e], o, 64);
    }

    if (lane == 0) {
        float lg[kE];
#pragma unroll
        for (int e = 0; e < kE; e++) lg[e] = (float)acc[e];
#pragma unroll
        for (int e = 0; e < kE; e++) logits_out[(size_t)t * kE + e] = lg[e];

        // top-2, first-index-wins on ties (np/jax semantics)
        int e0 = 0; float l0 = lg[0];
        for (int e = 1; e < kE; e++) if (lg[e] > l0) { l0 = lg[e]; e0 = e; }
        int e1 = -1; float l1 = -3.4e38f;
        for (int e = 0; e < kE; e++) if (e != e0 && lg[e] > l1) { l1 = lg[e]; e1 = e; }

        const float ex = __expf(l1 - l0);       // l1 <= l0
        const float w0 = 1.0f / (1.0f + ex);
        const float w1 = ex / (1.0f + ex);

        int s0 = atomicAdd(&counts[e0], 1);
        list[e0 * kT + s0] = t * 2 + 0;
        tw[t * 2 + 0] = w0;
        int s1 = atomicAdd(&counts[e1], 1);
        list[e1 * kT + s1] = t * 2 + 1;
        tw[t * 2 + 1] = w1;
    }
}

// ---------------------------------------------------------------- gather
// one block per global row (exactly 2T rows total)
__global__ void gather_kernel(const float* __restrict__ x, const int* __restrict__ list,
                              const int* __restrict__ counts, const int* __restrict__ offsets,
                              __bf16* __restrict__ xg, int* __restrict__ gentry) {
    const int g = blockIdx.x;                 // 0..2T-1
    int e = 0;
    while (e < kE - 1 && g >= offsets[e] + counts[e]) e++;
    const int s = g - offsets[e];
    const int entry = list[e * kT + s];
    const int t = entry >> 1;
    if (threadIdx.x == 0) gentry[g] = entry;  // inverse map for gemm2 scatter
    const int i = threadIdx.x * 4;
    const float4 v = *(const float4*)&x[(size_t)t * kH + i];
    __bf16 pk[4] = {(__bf16)v.x, (__bf16)v.y, (__bf16)v.z, (__bf16)v.w};
    *(ushort4*)&xg[(size_t)g * kH + i] = *(const ushort4*)pk;
}

// ---------------------------------------------------------------- weight transpose + cvt
// fp32 [R][C] -> bf16 [C][R], 64x64 tiles, float4 reads, ushort4 writes.
// z < nz selects (srcA,dstA) expert z, else (srcB,dstB) expert z-nz.
__global__ void transpose_cvt_kernel(const float* __restrict__ srcA, const float* __restrict__ srcB,
                                     __bf16* __restrict__ dstA, __bf16* __restrict__ dstB,
                                     int R, int C, int nz) {
    __shared__ float tile[64][65];
    const int z = blockIdx.z;
    const float* s;
    __bf16* d;
    if (z < nz) { s = srcA + (size_t)z * R * C;        d = dstA + (size_t)z * R * C; }
    else        { s = srcB + (size_t)(z - nz) * R * C; d = dstB + (size_t)(z - nz) * R * C; }
    const int r0 = blockIdx.y * 64, c0 = blockIdx.x * 64;
    const int tr = threadIdx.x >> 4;          // 0..15
    const int tc = (threadIdx.x & 15) * 4;    // 0,4,..,60
#pragma unroll
    for (int i = 0; i < 4; i++) {
        const float4 v = *(const float4*)&s[(size_t)(r0 + tr + i * 16) * C + (c0 + tc)];
        tile[tr + i * 16][tc + 0] = v.x;
        tile[tr + i * 16][tc + 1] = v.y;
        tile[tr + i * 16][tc + 2] = v.z;
        tile[tr + i * 16][tc + 3] = v.w;
    }
    __syncthreads();
#pragma unroll
    for (int i = 0; i < 4; i++) {
        const int oc = tr + i * 16;           // src col within tile = dst row
        __bf16 pk[4] = {(__bf16)tile[tc + 0][oc], (__bf16)tile[tc + 1][oc],
                        (__bf16)tile[tc + 2][oc], (__bf16)tile[tc + 3][oc]};
        *(ushort4*)&d[(size_t)(c0 + oc) * R + r0 + tc] = *(const ushort4*)pk;
    }
}

// ---------------------------------------------------------------- GEMM1 (dual-B, fused silu*mul)
// C1 = Xg @ W1t, C3 = Xg @ W3t ; act = bf16(silu(C1)*C3)
// LDS XOR swizzle per 128x32 sub-tile: slot (row,c) holds global phase
// c ^ (row&3) ^ ((row>>2)&3); staging scol / fragment sw are per-lane consts.
// BK=64: two sub-tiles staged per barrier pair -> 2x MFMA per vmcnt drain.
__global__ __launch_bounds__(256, 2) void gemm1_kernel(
    const __bf16* __restrict__ xg, const __bf16* __restrict__ w1t,
    const __bf16* __restrict__ w3t, __bf16* __restrict__ act,
    const int* __restrict__ counts, const int* __restrict__ offsets) {
    const int e = blockIdx.z;
    const int cnt = counts[e];
    const int m0 = blockIdx.y * 128;
    if (m0 >= cnt) return;
    const int n0 = blockIdx.x * 128;
    const int off = offsets[e];

    // [2 sub-tiles][128 rows][32 cols] per matrix = 16 KB each, 48 KB total
    __shared__ __bf16 As[2 * 4096], B1s[2 * 4096], B3s[2 * 4096];

    const int tid = threadIdx.x;
    const int lane = tid & 63, wave = tid >> 6;
    const int wm = (wave >> 1) * 64, wn = (wave & 1) * 64;
    const int lrow = lane & 15, quad = lane >> 4;

    // staging: lane stages LDS slot (row = p*64 + tid/4, phase = tid&3) and must
    // fetch global phase (tid&3) ^ ((tid>>2)&3) ^ ((tid>>4)&3)
    const int scol = (((tid & 3) ^ ((tid >> 2) & 3) ^ ((tid >> 4) & 3))) * 8;
    const __bf16* abase[2];
    const __bf16* b1base[2];
    const __bf16* b3base[2];
    const __bf16* w1b = w1t + (size_t)e * kI * kH + (size_t)n0 * kH;
    const __bf16* w3b = w3t + (size_t)e * kI * kH + (size_t)n0 * kH;
#pragma unroll
    for (int p = 0; p < 2; p++) {
        const int r = p * 64 + (tid >> 2);
        const int gr = min(m0 + r, cnt - 1);           // clamp for partial tiles
        abase[p]  = xg + (size_t)(off + gr) * kH + scol;
        b1base[p] = w1b + (size_t)r * kH + scol;
        b3base[p] = w3b + (size_t)r * kH + scol;
    }

    // fragment reads: swizzled phase = quad ^ (lrow&3) ^ ((lrow>>2)&3)
    const int sw = (lane & 3) ^ ((lane >> 2) & 3);
    const int fragoff = lrow * 32 + ((quad ^ sw) * 8);

    v4f acc1[4][4], acc3[4][4];
#pragma unroll
    for (int i = 0; i < 4; i++)
#pragma unroll
        for (int j = 0; j < 4; j++) { acc1[i][j] = (v4f)0.0f; acc3[i][j] = (v4f)0.0f; }

    for (int kt = 0; kt < kH / 64; kt++) {
        const int k0 = kt * 64;
        // stage both 32-wide sub-tiles (identical layout/swizzle each)
#pragma unroll
        for (int h = 0; h < 2; h++) {
#pragma unroll
            for (int p = 0; p < 2; p++) {
                const int soff = h * 4096 + p * 2048 + tid * 8;   // elements
                async16(&As[soff],  abase[p]  + k0 + h * 32);
                async16(&B1s[soff], b1base[p] + k0 + h * 32);
                async16(&B3s[soff], b3base[p] + k0 + h * 32);
            }
        }
        __syncthreads();

#pragma unroll
        for (int h = 0; h < 2; h++) {
            const int base = h * 4096;
            v8bf a[4];
#pragma unroll
            for (int fm = 0; fm < 4; fm++)
                a[fm] = *(const v8bf*)&As[base + (wm + fm * 16) * 32 + fragoff];
#pragma unroll
            for (int fn = 0; fn < 4; fn++) {
                const v8bf b1 = *(const v8bf*)&B1s[base + (wn + fn * 16) * 32 + fragoff];
                const v8bf b3 = *(const v8bf*)&B3s[base + (wn + fn * 16) * 32 + fragoff];
#pragma unroll
                for (int fm = 0; fm < 4; fm++) {
                    acc1[fm][fn] = __builtin_amdgcn_mfma_f32_16x16x32_bf16(a[fm], b1, acc1[fm][fn], 0, 0, 0);
                    acc3[fm][fn] = __builtin_amdgcn_mfma_f32_16x16x32_bf16(a[fm], b3, acc3[fm][fn], 0, 0, 0);
                }
            }
        }
        __syncthreads();
    }

    // epilogue: silu(c1)*c3 -> bf16 act
#pragma unroll
    for (int fm = 0; fm < 4; fm++) {
#pragma unroll
        for (int fn = 0; fn < 4; fn++) {
            const v4f c1 = acc1[fm][fn], c3 = acc3[fm][fn];
            const int col = n0 + wn + fn * 16 + lrow;
#pragma unroll
            for (int r = 0; r < 4; r++) {
                const int gm = m0 + wm + fm * 16 + quad * 4 + r;
                if (gm < cnt) {
                    const float h1 = c1[r], h3 = c3[r];
                    const float v = h1 / (1.0f + __expf(-h1)) * h3;
                    act[(size_t)(off + gm) * kI + col] = (__bf16)v;
                }
            }
        }
    }
}

// ---------------------------------------------------------------- GEMM2 (+fused combine)
// out[t] += tw[entry] * (act @ W2t)[g]  via atomicAdd; exactly 2 adds/element,
// fp32 add commutative -> bit-deterministic. BK=64, single-buffered (32 KB LDS).
// ~160 unified regs -> 3 blocks/CU.
__global__ __launch_bounds__(256, 3) void gemm2_kernel(
    const __bf16* __restrict__ act, const __bf16* __restrict__ w2t,
    float* __restrict__ out, const float* __restrict__ tw,
    const int* __restrict__ gentry,
    const int* __restrict__ counts, const int* __restrict__ offsets) {
    const int e = blockIdx.z;
    const int cnt = counts[e];
    const int m0 = blockIdx.y * 128;
    if (m0 >= cnt) return;
    const int n0 = blockIdx.x * 128;
    const int off = offsets[e];

    __shared__ __bf16 As[2 * 4096], Bs[2 * 4096];

    const int tid = threadIdx.x;
    const int lane = tid & 63, wave = tid >> 6;
    const int wm = (wave >> 1) * 64, wn = (wave & 1) * 64;
    const int lrow = lane & 15, quad = lane >> 4;

    const int scol = (((tid & 3) ^ ((tid >> 2) & 3) ^ ((tid >> 4) & 3))) * 8;
    const __bf16* abase[2];
    const __bf16* bbase[2];
    const __bf16* w2b = w2t + (size_t)e * kH * kI + (size_t)n0 * kI;
#pragma unroll
    for (int p = 0; p < 2; p++) {
        const int r = p * 64 + (tid >> 2);
        const int gr = min(m0 + r, cnt - 1);
        abase[p] = act + (size_t)(off + gr) * kI + scol;
        bbase[p] = w2b + (size_t)r * kI + scol;
    }

    const int sw = (lane & 3) ^ ((lane >> 2) & 3);
    const int fragoff = lrow * 32 + ((quad ^ sw) * 8);

    v4f acc[4][4];
#pragma unroll
    for (int i = 0; i < 4; i++)
#pragma unroll
        for (int j = 0; j < 4; j++) acc[i][j] = (v4f)0.0f;

    for (int kt = 0; kt < kI / 64; kt++) {
        const int k0 = kt * 64;
#pragma unroll
        for (int h = 0; h < 2; h++) {
#pragma unroll
            for (int p = 0; p < 2; p++) {
                const int soff = h * 4096 + p * 2048 + tid * 8;
                async16(&As[soff], abase[p] + k0 + h * 32);
                async16(&Bs[soff], bbase[p] + k0 + h * 32);
            }
        }
        __syncthreads();

#pragma unroll
        for (int h = 0; h < 2; h++) {
            const int base = h * 4096;
            v8bf a[4];
#pragma unroll
            for (int fm = 0; fm < 4; fm++)
                a[fm] = *(const v8bf*)&As[base + (wm + fm * 16) * 32 + fragoff];
#pragma unroll
            for (int fn = 0; fn < 4; fn++) {
                const v8bf b = *(const v8bf*)&Bs[base + (wn + fn * 16) * 32 + fragoff];
#pragma unroll
                for (int fm = 0; fm < 4; fm++)
                    acc[fm][fn] = __builtin_amdgcn_mfma_f32_16x16x32_bf16(a[fm], b, acc[fm][fn], 0, 0, 0);
            }
        }
        __syncthreads();
    }

#pragma unroll
    for (int fm = 0; fm < 4; fm++) {
#pragma unroll
        for (int r = 0; r < 4; r++) {
            const int gm = m0 + wm + fm * 16 + quad * 4 + r;
            if (gm < cnt) {
                const int entry = gentry[off + gm];      // broadcast across 16 lanes
                const int t = entry >> 1;
                const float w = tw[entry];
#pragma unroll
                for (int fn = 0; fn < 4; fn++) {
                    const int col = n0 + wn + fn * 16 + lrow;
                    atomicAdd(&out[(size_t)t * kH + col], w * acc[fm][fn][r]);
                }
            }
        }
    }
}

// ---------------------------------------------------------------- launch
extern "C" void kernel_launch(void* const* d_in, const int* in_sizes, int n_in,
                              void* d_out, int out_size, void* d_ws, size_t ws_size,
                              hipStream_t stream) {
    const float* x  = (const float*)d_in[0];
    const float* gw = (const float*)d_in[1];
    const float* w1 = (const float*)d_in[2];
    const float* w3 = (const float*)d_in[3];
    const float* w2 = (const float*)d_in[4];
    float* out = (float*)d_out;
    float* logits_out = out + (size_t)kT * kH;

    char* ws = (char*)d_ws;
    __bf16* w1t   = (__bf16*)(ws + OFF_W1T);
    __bf16* w3t   = (__bf16*)(ws + OFF_W3T);
    __bf16* w2t   = (__bf16*)(ws + OFF_W2T);
    __bf16* xg    = (__bf16*)(ws + OFF_XG);
    __bf16* act   = (__bf16*)(ws + OFF_ACT);
    int*    cnt   = (int*)   (ws + OFF_CNT);
    int*    ofs   = (int*)   (ws + OFF_OFS);
    int*    list  = (int*)   (ws + OFF_LST);
    float*  tw    = (float*) (ws + OFF_TW);
    int*    gent  = (int*)   (ws + OFF_GE);

    zero_counts_kernel<<<1, 64, 0, stream>>>(cnt);
    // zero the hidden-state part of out (gemm2 accumulates into it atomically)
    hipMemsetAsync(out, 0, (size_t)kT * kH * sizeof(float), stream);

    // w1 [H][I] -> [I][H] and w3 likewise, fused in one launch (z = 16)
    transpose_cvt_kernel<<<dim3(kI / 64, kH / 64, 2 * kE), 256, 0, stream>>>(
        w1, w3, w1t, w3t, kH, kI, kE);
    // w2 [I][H] -> [H][I]
    transpose_cvt_kernel<<<dim3(kH / 64, kI / 64, kE), 256, 0, stream>>>(
        w2, w2, w2t, w2t, kI, kH, kE);

    router_kernel<<<kT / 4, 256, 0, stream>>>(x, gw, logits_out, tw, cnt, list);
    prefix_kernel<<<1, 1, 0, stream>>>(cnt, ofs);
    gather_kernel<<<2 * kT, 256, 0, stream>>>(x, list, cnt, ofs, xg, gent);

    gemm1_kernel<<<dim3(kI / 128, kT / 128, kE), 256, 0, stream>>>(xg, w1t, w3t, act, cnt, ofs);
    gemm2_kernel<<<dim3(kH / 128, kT / 128, kE), 256, 0, stream>>>(act, w2t, out, tw, gent, cnt, ofs);
}